// Round 13
// baseline (273.072 us; speedup 1.0000x reference)
//
#include <hip/hip_runtime.h>

// ---------------------------------------------------------------------------
// RegionalCrossAttention on MI355X (gfx950).  fp32 in / fp32 out.
// B=2, n=8, L=4096, Lt=77, d=1024, ctx=768, H=16 heads x 64.
//
// Round-20 changes vs round-19 (250.9 us; proj_qkv 66 us GRID-limited at
// 2-3 blocks/CU -- occupancy 21.5%, not an LDS/VGPR limit):
//  * Q GEMM and WO GEMM re-tiled 128x128 -> 128m x 64n (4 waves of 32x64,
//    acc[2][4]).  LDS 32768 -> 24576 B; Q grid 512 -> 1024 blocks
//    (proj total 1280 = 5 blocks/CU), wo grid 512 -> 1024 (4 blocks/CU).
//    Same m97 global_load_lds dbuf staging, same 1 barrier/kt -- 2.5x more
//    co-resident blocks to cover each barrier drain (the m114 mechanism).
//  * Everything else byte-identical to round-19.
// ---------------------------------------------------------------------------

typedef __bf16 bf16;
typedef __bf16 bf16x8 __attribute__((ext_vector_type(8)));
typedef __bf16 bf16x4 __attribute__((ext_vector_type(4)));
typedef float  f32x4  __attribute__((ext_vector_type(4)));

#define MFMA16(a, b, c) __builtin_amdgcn_mfma_f32_16x16x32_bf16((a), (b), (c), 0, 0, 0)

// v_mfma_f32_16x16x32_bf16 layouts (HW-verified, learn_hip m89/m120):
//   A: lane holds A[m = lane&15][k = 8*(lane>>4) + j], j=0..7
//   B: lane holds B[k = 8*(lane>>4) + j][n = lane&15]
//   D: lane,reg r holds D[m = 4*(lane>>4) + r][n = lane&15]

__device__ inline bf16x8 cvt8(const float* p) {
  f32x4 a = *(const f32x4*)p;
  f32x4 b = *(const f32x4*)(p + 4);
  bf16x8 r;
  r[0] = (bf16)a[0]; r[1] = (bf16)a[1]; r[2] = (bf16)a[2]; r[3] = (bf16)a[3];
  r[4] = (bf16)b[0]; r[5] = (bf16)b[1]; r[6] = (bf16)b[2]; r[7] = (bf16)b[3];
  return r;
}

// direct global->LDS DMA, 16B per lane; LDS dest = wave-uniform base + lane*16
__device__ __forceinline__ void gload_lds16(const bf16* g, bf16* l) {
  __builtin_amdgcn_global_load_lds(
      (const __attribute__((address_space(1))) void*)g,
      (__attribute__((address_space(3))) void*)l, 16, 0, 0);
}

// ---------------------------------------------------------------------------
// Weight transposes + cover + x->bf16 conversion, one launch.  grid=(32,145).
// ---------------------------------------------------------------------------
__global__ __launch_bounds__(256) void transpose_all(
    const float* __restrict__ Wq, const float* __restrict__ Wk,
    const float* __restrict__ Wv, const float* __restrict__ Wo,
    bf16* __restrict__ WqT, bf16* __restrict__ WkT,
    bf16* __restrict__ WvT, bf16* __restrict__ WoT,
    const float* __restrict__ mask, float* __restrict__ cover,
    const float* __restrict__ x, bf16* __restrict__ xb) {
  __shared__ bf16 tile[32][33];
  int bx = blockIdx.x;
  int byg = blockIdx.y;
  if (byg == 112) {
    int tid = bx * 256 + threadIdx.x;
    int b = tid >> 12, l = tid & 4095;
    float c = 0.f;
#pragma unroll
    for (int n = 0; n < 8; n++)
      c += (mask[(size_t)(b * 8 + n) * 4096 + l] > 0.5f) ? 1.f : 0.f;
    cover[tid] = c;
    return;
  }
  if (byg >= 113) {
    int gy = byg - 113;  // 0..31
    const size_t blk = (size_t)(gy * 32 + bx) * 1024;
#pragma unroll
    for (int i = 0; i < 4; i++) {
      size_t e = (blk + i * 256 + threadIdx.x) * 8;
      *(bf16x8*)(xb + e) = cvt8(x + e);
    }
    return;
  }
  int tx = threadIdx.x & 31, ty = threadIdx.x >> 5;
  const float* in;
  bf16* out;
  int R, by;
  if (byg < 32)      { in = Wq; out = WqT; R = 1024; by = byg; }
  else if (byg < 56) { in = Wk; out = WkT; R = 768;  by = byg - 32; }
  else if (byg < 80) { in = Wv; out = WvT; R = 768;  by = byg - 56; }
  else               { in = Wo; out = WoT; R = 1024; by = byg - 80; }
  const int C = 1024;
  int c = bx * 32 + tx;
#pragma unroll
  for (int i = 0; i < 32; i += 8) {
    int r = by * 32 + ty + i;
    tile[ty + i][tx] = (bf16)in[(size_t)r * C + c];
  }
  __syncthreads();
#pragma unroll
  for (int i = 0; i < 32; i += 8) {
    out[(size_t)(bx * 32 + ty + i) * R + by * 32 + tx] = tile[tx][ty + i];
  }
}

// ---------------------------------------------------------------------------
// Q GEMM body, m97 structure, 128m x 64n tile: Qb = (xb @ WqT^T) * 0.125.
// 4 waves of 32m x 64n (acc 2x4), BK=32, dbuf LDS staged by global_load_lds
// w16: A = 512 chunks (2 issues/thread), B = 256 chunks (1 issue/thread).
// Stage(next) issued BEFORE ds_read+MFMA of cur; one __syncthreads per kt.
// LDS 24576 B -> 6 blocks/CU allowed; grid 1024 Q blocks.
// ---------------------------------------------------------------------------
__device__ __forceinline__ void gemm_q_body(const bf16* __restrict__ Ab,
                                            const bf16* __restrict__ BT,
                                            bf16* __restrict__ C,
                                            int bxn, int bym) {
  __shared__ __align__(16) bf16 sA[2][128 * 32];
  __shared__ __align__(16) bf16 sB[2][64 * 32];
  const int tid = threadIdx.x;
  const int lane = tid & 63, wave = tid >> 6;
  const int l16 = lane & 15, quad = lane >> 4;
  const int m0 = bym * 128, n0 = bxn * 64;
  const int wm = wave * 32;

  // A chunks: issue0 = tid, issue1 = 256+tid; B chunk = tid
  const int a0r = tid >> 2,        a0c = (tid & 3) * 8;
  const int a1r = (256 + tid) >> 2, a1c = ((256 + tid) & 3) * 8;
  const int lo0 = (wave * 64) * 8;          // element offset, chunk-base*8
  const int lo1 = (256 + wave * 64) * 8;

  const bf16* Arow0 = Ab + (size_t)(m0 + a0r) * 1024 + a0c;
  const bf16* Arow1 = Ab + (size_t)(m0 + a1r) * 1024 + a1c;
  const bf16* Brow  = BT + (size_t)(n0 + a0r) * 1024 + a0c;

  // prologue: stage kt=0 into buffer 0
  gload_lds16(Arow0, &sA[0][lo0]);
  gload_lds16(Arow1, &sA[0][lo1]);
  gload_lds16(Brow,  &sB[0][lo0]);

  f32x4 acc[2][4];
#pragma unroll
  for (int i = 0; i < 2; i++)
#pragma unroll
    for (int j = 0; j < 4; j++)
#pragma unroll
      for (int r = 0; r < 4; r++) acc[i][j][r] = 0.f;

  __syncthreads();

  int cur = 0;
  for (int kt = 0; kt < 32; kt++) {
    if (kt + 1 < 32) {
      const int nb = cur ^ 1, ko = (kt + 1) * 32;
      gload_lds16(Arow0 + ko, &sA[nb][lo0]);
      gload_lds16(Arow1 + ko, &sA[nb][lo1]);
      gload_lds16(Brow + ko,  &sB[nb][lo0]);
    }
    bf16x8 a[2], b[4];
#pragma unroll
    for (int mi = 0; mi < 2; mi++)
      a[mi] = *(const bf16x8*)(&sA[cur][(wm + mi * 16 + l16) * 32 + quad * 8]);
#pragma unroll
    for (int ni = 0; ni < 4; ni++)
      b[ni] = *(const bf16x8*)(&sB[cur][(ni * 16 + l16) * 32 + quad * 8]);
#pragma unroll
    for (int mi = 0; mi < 2; mi++)
#pragma unroll
      for (int ni = 0; ni < 4; ni++) acc[mi][ni] = MFMA16(a[mi], b[ni], acc[mi][ni]);
    __syncthreads();
    cur ^= 1;
  }

#pragma unroll
  for (int mi = 0; mi < 2; mi++)
#pragma unroll
    for (int r = 0; r < 4; r++) {
      int row = m0 + wm + mi * 16 + quad * 4 + r;
#pragma unroll
      for (int ni = 0; ni < 4; ni++)
        C[(size_t)row * 1024 + n0 + ni * 16 + l16] = (bf16)(acc[mi][ni][r] * 0.125f);
    }
}

// ---------------------------------------------------------------------------
// K projection body with padded store: Kp[bn][80][1024] bf16; rows 77..79 = 0.
// ---------------------------------------------------------------------------
__device__ __forceinline__ void gemm_k_body(const float* __restrict__ text,
                                            const bf16* __restrict__ WkT,
                                            bf16* __restrict__ Kp,
                                            int bx, int bn) {
  const int tid = threadIdx.x;
  const int lane = tid & 63, wave = tid >> 6;
  const int l16 = lane & 15, quad = lane >> 4;
  const int m0 = (wave >> 1) * 64;
  const int n0 = bx * 128 + (wave & 1) * 64;
  const float* A = text + (size_t)bn * 77 * 768;
  bf16* dst = Kp + (size_t)bn * 80 * 1024;

  f32x4 acc[4][4];
#pragma unroll
  for (int i = 0; i < 4; i++)
#pragma unroll
    for (int j = 0; j < 4; j++)
#pragma unroll
      for (int r = 0; r < 4; r++) acc[i][j][r] = 0.f;

  for (int k0 = 0; k0 < 768; k0 += 32) {
    bf16x8 a[4], b[4];
#pragma unroll
    for (int mi = 0; mi < 4; mi++) {
      int row = m0 + mi * 16 + l16;
      if (row >= 77) row = 76;
      a[mi] = cvt8(A + (size_t)row * 768 + k0 + quad * 8);
    }
#pragma unroll
    for (int ni = 0; ni < 4; ni++)
      b[ni] = *(const bf16x8*)(WkT + (size_t)(n0 + ni * 16 + l16) * 768 + k0 + quad * 8);
#pragma unroll
    for (int mi = 0; mi < 4; mi++)
#pragma unroll
      for (int ni = 0; ni < 4; ni++) acc[mi][ni] = MFMA16(a[mi], b[ni], acc[mi][ni]);
  }

#pragma unroll
  for (int mi = 0; mi < 4; mi++)
#pragma unroll
    for (int r = 0; r < 4; r++) {
      int t = m0 + mi * 16 + quad * 4 + r;
      if (t < 77) {
#pragma unroll
        for (int ni = 0; ni < 4; ni++)
          dst[(size_t)t * 1024 + n0 + ni * 16 + l16] = (bf16)acc[mi][ni][r];
      } else if (t < 80) {
#pragma unroll
        for (int ni = 0; ni < 4; ni++)
          dst[(size_t)t * 1024 + n0 + ni * 16 + l16] = (bf16)0.f;
      }
    }
}

// ---------------------------------------------------------------------------
// V projection body with TRANSPOSED padded store: Vt[bn][1024][96] bf16.
// ---------------------------------------------------------------------------
__device__ __forceinline__ void gemm_v_body(const float* __restrict__ text,
                                            const bf16* __restrict__ WvT,
                                            bf16* __restrict__ Vt,
                                            int bx, int bn) {
  const int tid = threadIdx.x;
  const int lane = tid & 63, wave = tid >> 6;
  const int l16 = lane & 15, quad = lane >> 4;
  const int m0 = (wave >> 1) * 64;
  const int n0 = bx * 128 + (wave & 1) * 64;
  const float* A = text + (size_t)bn * 77 * 768;
  bf16* dst = Vt + (size_t)bn * 1024 * 96;

  f32x4 acc[4][4];
#pragma unroll
  for (int i = 0; i < 4; i++)
#pragma unroll
    for (int j = 0; j < 4; j++)
#pragma unroll
      for (int r = 0; r < 4; r++) acc[i][j][r] = 0.f;

  for (int k0 = 0; k0 < 768; k0 += 32) {
    bf16x8 a[4], b[4];
#pragma unroll
    for (int mi = 0; mi < 4; mi++) {
      int row = m0 + mi * 16 + l16;
      if (row >= 77) row = 76;
      a[mi] = cvt8(A + (size_t)row * 768 + k0 + quad * 8);
    }
#pragma unroll
    for (int ni = 0; ni < 4; ni++)
      b[ni] = *(const bf16x8*)(WvT + (size_t)(n0 + ni * 16 + l16) * 768 + k0 + quad * 8);
#pragma unroll
    for (int mi = 0; mi < 4; mi++)
#pragma unroll
      for (int ni = 0; ni < 4; ni++) acc[mi][ni] = MFMA16(a[mi], b[ni], acc[mi][ni]);
  }

#pragma unroll
  for (int mi = 0; mi < 4; mi++) {
    int t0 = m0 + mi * 16 + quad * 4;
#pragma unroll
    for (int ni = 0; ni < 4; ni++) {
      int col = n0 + ni * 16 + l16;
      bf16* cbase = dst + (size_t)col * 96;
      if (t0 + 3 < 77) {
        bf16x4 w;
        w[0] = (bf16)acc[mi][ni][0]; w[1] = (bf16)acc[mi][ni][1];
        w[2] = (bf16)acc[mi][ni][2]; w[3] = (bf16)acc[mi][ni][3];
        *(bf16x4*)(cbase + t0) = w;
      } else {
#pragma unroll
        for (int r = 0; r < 4; r++) {
          int t = t0 + r;
          if (t < 77)      cbase[t] = (bf16)acc[mi][ni][r];
          else if (t < 96) cbase[t] = (bf16)0.f;
        }
      }
    }
  }
}

// ---------------------------------------------------------------------------
// Fused Q + K + V projections.  Flat grid of qcount+256 blocks:
//   bid < qcount : Q GEMM  (bym = bid & 63, bxn = bid >> 6); qcount=1024 fast
//   bid >= qcount: K/V     (r = bid-qcount: bx = r&7, bn = (r>>3)&15, z=r>>7)
// ---------------------------------------------------------------------------
__global__ __launch_bounds__(256) void proj_qkv(const bf16* __restrict__ xb,
                                                const bf16* __restrict__ WqT,
                                                bf16* __restrict__ Qb,
                                                const float* __restrict__ text,
                                                const bf16* __restrict__ WkT,
                                                const bf16* __restrict__ WvT,
                                                bf16* __restrict__ Kp,
                                                bf16* __restrict__ Vt,
                                                int qcount) {
  const int bid = blockIdx.x;
  if (bid < qcount) {
    gemm_q_body(xb, WqT, Qb, bid >> 6, bid & 63);
  } else {
    const int r = bid - qcount;
    const int bx = r & 7, bn = (r >> 3) & 15, kz = r >> 7;
    if (kz == 0) gemm_k_body(text, WkT, Kp, bx, bn);
    else         gemm_v_body(text, WvT, Vt, bx, bn);
  }
}

// Q GEMM (fallback): fp32 in, fp32 out, pre-scaled by 0.125
__global__ __launch_bounds__(256) void gemm_q_f(const float* __restrict__ A,
                                                const bf16* __restrict__ BT,
                                                float* __restrict__ C) {
  const int tid = threadIdx.x;
  const int lane = tid & 63, wave = tid >> 6;
  const int l16 = lane & 15, quad = lane >> 4;
  const int m0 = blockIdx.y * 64;
  const int n0 = blockIdx.x * 256 + wave * 64;

  f32x4 acc[4][4];
#pragma unroll
  for (int i = 0; i < 4; i++)
#pragma unroll
    for (int j = 0; j < 4; j++)
#pragma unroll
      for (int r = 0; r < 4; r++) acc[i][j][r] = 0.f;

  for (int kt = 0; kt < 32; kt++) {
    bf16x8 a[4], b[4];
#pragma unroll
    for (int mi = 0; mi < 4; mi++)
      a[mi] = cvt8(A + (size_t)(m0 + mi * 16 + l16) * 1024 + kt * 32 + quad * 8);
#pragma unroll
    for (int ni = 0; ni < 4; ni++)
      b[ni] = *(const bf16x8*)(BT + (size_t)(n0 + ni * 16 + l16) * 1024 + kt * 32 + quad * 8);
#pragma unroll
    for (int mi = 0; mi < 4; mi++)
#pragma unroll
      for (int ni = 0; ni < 4; ni++) acc[mi][ni] = MFMA16(a[mi], b[ni], acc[mi][ni]);
  }

#pragma unroll
  for (int mi = 0; mi < 4; mi++)
#pragma unroll
    for (int r = 0; r < 4; r++) {
      int row = m0 + mi * 16 + quad * 4 + r;
#pragma unroll
      for (int ni = 0; ni < 4; ni++)
        C[(size_t)row * 1024 + n0 + ni * 16 + l16] = acc[mi][ni][r] * 0.125f;
    }
}

// ---------------------------------------------------------------------------
// Attention core (round-8 staging structure + joint-mi PV).
// LDS: kl 11520 + vl 13312 + p_lds 13312 = 38144 B -> 4 blocks/CU.
// ---------------------------------------------------------------------------
template <typename OutT, typename InT>
__device__ __forceinline__ void attn_body(const InT* Qsrc, OutT* Odst,
                                          const bf16* __restrict__ Kp,
                                          const bf16* __restrict__ Vt,
                                          const float* __restrict__ mask) {
  __shared__ __align__(16) bf16 kl[80 * 72];
  __shared__ __align__(16) bf16 vl[64 * 104];
  __shared__ __align__(16) bf16 p_lds[4][16 * 104];
  const int tid = threadIdx.x;
  const int lane = tid & 63, wave = tid >> 6;
  const int l16 = lane & 15, quad = lane >> 4;
  const int bid = blockIdx.x;
  const int qg = bid & 31;
  const int h = (bid >> 5) & 15;
  const int b = bid >> 9;
  const int qrow0 = qg * 128 + wave * 32;
  bf16* pl = &p_lds[wave][0];

  for (int i = lane; i < 16 * 16; i += 64) {
    int r = i >> 4, c = 80 + (i & 15);
    pl[r * 104 + c] = (bf16)0.f;
  }

  bf16x8 qf[2][2];
#pragma unroll
  for (int mi = 0; mi < 2; mi++)
#pragma unroll
    for (int ks = 0; ks < 2; ks++) {
      const InT* qp = Qsrc + (size_t)(b * 4096 + qrow0 + mi * 16 + l16) * 1024 +
                      h * 64 + ks * 32 + quad * 8;
      if constexpr (sizeof(InT) == 4) qf[mi][ks] = cvt8((const float*)qp);
      else                            qf[mi][ks] = *(const bf16x8*)qp;
    }

  unsigned rbits[2];
#pragma unroll
  for (int mi = 0; mi < 2; mi++) {
    unsigned m = 0;
#pragma unroll
    for (int n = 0; n < 8; n++)
      if (mask[(size_t)(b * 8 + n) * 4096 + qrow0 + mi * 16 + l16] > 0.5f)
        m |= (1u << n);
    rbits[mi] = m;
  }

  f32x4 oacc[2][4];
#pragma unroll
  for (int mi = 0; mi < 2; mi++)
#pragma unroll
    for (int nt = 0; nt < 4; nt++)
#pragma unroll
      for (int r = 0; r < 4; r++) oacc[mi][nt][r] = 0.f;

  for (int n = 0; n < 8; n++) {
    const int bn = b * 8 + n;
    const bf16* Ksrc = Kp + (size_t)bn * 80 * 1024 + h * 64;
    const bf16* Vsrc = Vt + (size_t)bn * 1024 * 96 + (size_t)h * 64 * 96;

    for (int i = tid; i < 640; i += 256) {
      int row = i >> 3, c8 = (i & 7) * 8;
      *(bf16x8*)(kl + row * 72 + c8) = *(const bf16x8*)(Ksrc + (size_t)row * 1024 + c8);
    }
    for (int i = tid; i < 768; i += 256) {
      int row = i / 12, c8 = (i % 12) * 8;
      *(bf16x8*)(vl + row * 104 + c8) = *(const bf16x8*)(Vsrc + (size_t)row * 96 + c8);
    }
    __syncthreads();

    f32x4 s[2][5];
#pragma unroll
    for (int mi = 0; mi < 2; mi++)
#pragma unroll
      for (int tt = 0; tt < 5; tt++)
#pragma unroll
        for (int r = 0; r < 4; r++) s[mi][tt][r] = 0.f;

#pragma unroll
    for (int tt = 0; tt < 5; tt++) {
      int t = tt * 16 + l16;
      bf16x8 kf0 = *(const bf16x8*)(kl + t * 72 + quad * 8);
      bf16x8 kf1 = *(const bf16x8*)(kl + t * 72 + 32 + quad * 8);
#pragma unroll
      for (int mi = 0; mi < 2; mi++) {
        s[mi][tt] = MFMA16(kf0, qf[mi][0], s[mi][tt]);
        s[mi][tt] = MFMA16(kf1, qf[mi][1], s[mi][tt]);
      }
    }

    bf16x8 pfr[2][3];
#pragma unroll
    for (int mi = 0; mi < 2; mi++) {
      float sum = 0.f;
#pragma unroll
      for (int tt = 0; tt < 5; tt++) {
#pragma unroll
        for (int r = 0; r < 4; r++) {
          float e = __expf(s[mi][tt][r]);  // 0.125 scale folded into Q GEMM
          if (tt == 4 && quad * 4 + r >= 13) e = 0.f;
          s[mi][tt][r] = e;
          sum += e;
        }
      }
      sum += __shfl_xor(sum, 16);
      sum += __shfl_xor(sum, 32);
      float rg = ((rbits[mi] >> n) & 1u) ? 1.f : 0.f;
      float scale = rg / sum;
#pragma unroll
      for (int tt = 0; tt < 5; tt++) {
        bf16x4 w;
#pragma unroll
        for (int r = 0; r < 4; r++) w[r] = (bf16)(s[mi][tt][r] * scale);
        *(bf16x4*)(pl + l16 * 104 + tt * 16 + quad * 4) = w;
      }
#pragma unroll
      for (int ks = 0; ks < 3; ks++)
        pfr[mi][ks] = *(const bf16x8*)(pl + l16 * 104 + ks * 32 + quad * 8);
    }

#pragma unroll
    for (int ks = 0; ks < 3; ks++) {
#pragma unroll
      for (int nt = 0; nt < 4; nt++) {
        bf16x8 vf = *(const bf16x8*)(vl + (nt * 16 + l16) * 104 + ks * 32 + quad * 8);
        oacc[0][nt] = MFMA16(pfr[0][ks], vf, oacc[0][nt]);
        oacc[1][nt] = MFMA16(pfr[1][ks], vf, oacc[1][nt]);
      }
    }
    __syncthreads();
  }

#pragma unroll
  for (int mi = 0; mi < 2; mi++)
#pragma unroll
    for (int r = 0; r < 4; r++) {
      size_t row = (size_t)(b * 4096 + qrow0 + mi * 16 + quad * 4 + r);
#pragma unroll
      for (int nt = 0; nt < 4; nt++)
        Odst[row * 1024 + h * 64 + nt * 16 + l16] = (OutT)oacc[mi][nt][r];
    }
}

// fast: Q bf16 (in d_out), ACC bf16 (in ws)
__global__ __launch_bounds__(256, 4) void attn_b(const bf16* Qb, bf16* ACCb,
                                                 const bf16* __restrict__ Kp,
                                                 const bf16* __restrict__ Vt,
                                                 const float* __restrict__ mask) {
  attn_body<bf16, bf16>(Qb, ACCb, Kp, Vt, mask);
}
// fallback: fp32 in-place on d_out
__global__ __launch_bounds__(256, 4) void attn_f(float* QO,
                                                 const bf16* __restrict__ Kp,
                                                 const bf16* __restrict__ Vt,
                                                 const float* __restrict__ mask) {
  attn_body<float, float>(QO, QO, Kp, Vt, mask);
}

// ---------------------------------------------------------------------------
// Fast-path final GEMM, m97 structure, 128m x 64n tile: out = ACCb @ WoT^T
// + epilogue.  Same staged body as gemm_q_body; fp32 epilogue.
// grid = (16, 64).
// ---------------------------------------------------------------------------
__global__ __launch_bounds__(256) void gemm_wo_ep2(const bf16* __restrict__ A,
                                                   const bf16* __restrict__ BT,
                                                   const float* __restrict__ x,
                                                   const float* __restrict__ bo,
                                                   const float* __restrict__ nullf,
                                                   const float* __restrict__ cover,
                                                   float* __restrict__ out) {
  __shared__ __align__(16) bf16 sA[2][128 * 32];
  __shared__ __align__(16) bf16 sB[2][64 * 32];
  const int tid = threadIdx.x;
  const int lane = tid & 63, wave = tid >> 6;
  const int l16 = lane & 15, quad = lane >> 4;
  const int m0 = blockIdx.y * 128, n0 = blockIdx.x * 64;
  const int wm = wave * 32;

  const int a0r = tid >> 2,         a0c = (tid & 3) * 8;
  const int a1r = (256 + tid) >> 2, a1c = ((256 + tid) & 3) * 8;
  const int lo0 = (wave * 64) * 8;
  const int lo1 = (256 + wave * 64) * 8;

  const bf16* Arow0 = A + (size_t)(m0 + a0r) * 1024 + a0c;
  const bf16* Arow1 = A + (size_t)(m0 + a1r) * 1024 + a1c;
  const bf16* Brow  = BT + (size_t)(n0 + a0r) * 1024 + a0c;

  gload_lds16(Arow0, &sA[0][lo0]);
  gload_lds16(Arow1, &sA[0][lo1]);
  gload_lds16(Brow,  &sB[0][lo0]);

  f32x4 acc[2][4];
#pragma unroll
  for (int i = 0; i < 2; i++)
#pragma unroll
    for (int j = 0; j < 4; j++)
#pragma unroll
      for (int r = 0; r < 4; r++) acc[i][j][r] = 0.f;

  __syncthreads();

  int cur = 0;
  for (int kt = 0; kt < 32; kt++) {
    if (kt + 1 < 32) {
      const int nb = cur ^ 1, ko = (kt + 1) * 32;
      gload_lds16(Arow0 + ko, &sA[nb][lo0]);
      gload_lds16(Arow1 + ko, &sA[nb][lo1]);
      gload_lds16(Brow + ko,  &sB[nb][lo0]);
    }
    bf16x8 a[2], b[4];
#pragma unroll
    for (int mi = 0; mi < 2; mi++)
      a[mi] = *(const bf16x8*)(&sA[cur][(wm + mi * 16 + l16) * 32 + quad * 8]);
#pragma unroll
    for (int ni = 0; ni < 4; ni++)
      b[ni] = *(const bf16x8*)(&sB[cur][(ni * 16 + l16) * 32 + quad * 8]);
#pragma unroll
    for (int mi = 0; mi < 2; mi++)
#pragma unroll
      for (int ni = 0; ni < 4; ni++) acc[mi][ni] = MFMA16(a[mi], b[ni], acc[mi][ni]);
    __syncthreads();
    cur ^= 1;
  }

#pragma unroll
  for (int mi = 0; mi < 2; mi++)
#pragma unroll
    for (int r = 0; r < 4; r++) {
      int row = m0 + wm + mi * 16 + quad * 4 + r;
      float cv = cover[row];
#pragma unroll
      for (int ni = 0; ni < 4; ni++) {
        int col = n0 + ni * 16 + l16;
        float v = acc[mi][ni][r] + cv * bo[col] + (1.f - cv) * nullf[col] +
                  x[(size_t)row * 1024 + col];
        out[(size_t)row * 1024 + col] = v;
      }
    }
}

// ---------------------------------------------------------------------------
// Fallback in-place final GEMM (round-7 version).
// ---------------------------------------------------------------------------
__global__ __launch_bounds__(512) void gemm_wo_ep(float* QO,
                                                  const bf16* __restrict__ WoT,
                                                  const float* __restrict__ x,
                                                  const float* __restrict__ bo,
                                                  const float* __restrict__ nullf,
                                                  const float* __restrict__ cover) {
  __shared__ __align__(16) bf16 lds_a[32 * 32 * 32];
  const int tid = threadIdx.x;
  const int lane = tid & 63, wv = tid >> 6;
  const int l16 = lane & 15, quad = lane >> 4;
  const int m0 = blockIdx.x * 32;

#pragma unroll
  for (int c = 0; c < 16; c++) {
    int ch = c * 512 + tid;
    int row = ch >> 8;
    int pos4 = (ch & 255) * 4;
    int kt = pos4 >> 5, kin = pos4 & 31;
    f32x4 v = *(const f32x4*)(QO + (size_t)(m0 + row) * 1024 + pos4);
    bf16x4 w;
    w[0] = (bf16)v[0]; w[1] = (bf16)v[1]; w[2] = (bf16)v[2]; w[3] = (bf16)v[3];
    *(bf16x4*)(lds_a + kt * 1024 + row * 32 + kin) = w;
  }
  __syncthreads();

  const int n0 = wv * 128;
  f32x4 acc[2][8];
#pragma unroll
  for (int mi = 0; mi < 2; mi++)
#pragma unroll
    for (int ni = 0; ni < 8; ni++)
#pragma unroll
      for (int r = 0; r < 4; r++) acc[mi][ni][r] = 0.f;

  for (int kt = 0; kt < 32; kt++) {
    bf16x8 a[2];
#pragma unroll
    for (int mi = 0; mi < 2; mi++)
      a[mi] = *(const bf16x8*)(lds_a + kt * 1024 + (mi * 16 + l16) * 32 + quad * 8);
    bf16x8 bfr[8];
#pragma unroll
    for (int ni = 0; ni < 8; ni++)
      bfr[ni] = *(const bf16x8*)(WoT + (size_t)(n0 + ni * 16 + l16) * 1024 + kt * 32 + quad * 8);
#pragma unroll
    for (int mi = 0; mi < 2; mi++)
#pragma unroll
      for (int ni = 0; ni < 8; ni++) acc[mi][ni] = MFMA16(a[mi], bfr[ni], acc[mi][ni]);
  }

#pragma unroll
  for (int mi = 0; mi < 2; mi++)
#pragma unroll
    for (int r = 0; r < 4; r++) {
      int row = m0 + mi * 16 + quad * 4 + r;
      float cv = cover[row];
#pragma unroll
      for (int ni = 0; ni < 8; ni++) {
        int col = n0 + ni * 16 + l16;
        float v = acc[mi][ni][r] + cv * bo[col] + (1.f - cv) * nullf[col] +
                  x[(size_t)row * 1024 + col];
        QO[(size_t)row * 1024 + col] = v;
      }
    }
}

// ---------------------------------------------------------------------------
extern "C" void kernel_launch(void* const* d_in, const int* in_sizes, int n_in,
                              void* d_out, int out_size, void* d_ws, size_t ws_size,
                              hipStream_t stream) {
  const float* x     = (const float*)d_in[0];
  const float* masks = (const float*)d_in[1];
  const float* text  = (const float*)d_in[2];
  const float* Wq    = (const float*)d_in[3];
  const float* Wk    = (const float*)d_in[4];
  const float* Wv    = (const float*)d_in[5];
  const float* Wo    = (const float*)d_in[6];
  const float* bo    = (const float*)d_in[7];
  const float* nullf = (const float*)d_in[8];
  float* out = (float*)d_out;

  bf16* ws  = (bf16*)d_ws;
  bf16* WqT = ws;                  // 1024*1024
  bf16* WkT = WqT + 1048576;       // 1024*768
  bf16* WvT = WkT + 786432;        // 1024*768
  bf16* WoT = WvT + 786432;        // 1024*1024
  bf16* Kp  = WoT + 1048576;       // 16*80*1024
  bf16* Vt  = Kp + 1310720;        // 16*1024*96
  float* cover = (float*)(Vt + 1572864);          // 8192 f32
  bf16* ACCb = (bf16*)(cover + 8192);             // 8192*1024 bf16 (fast path)
  const size_t NEEDED = 13139968 + 16777216;      // 29,917,184 B

  // d_out (32 MB) doubles as scratch before the final GEMM:
  //   first half  : Qb  bf16[8192*1024]
  //   second half : xb  bf16[8192*1024]  (x pre-converted)
  bf16* Qb = (bf16*)d_out;
  bf16* xb = (bf16*)d_out + 8388608;

  transpose_all<<<dim3(32, 145), 256, 0, stream>>>(Wq, Wk, Wv, Wo, WqT, WkT, WvT, WoT,
                                                   masks, cover, x, xb);

  if (ws_size >= NEEDED) {
    proj_qkv<<<1280, 256, 0, stream>>>(xb, WqT, Qb, text, WkT, WvT, Kp, Vt, 1024);
    attn_b<<<1024, 256, 0, stream>>>(Qb, ACCb, Kp, Vt, masks);
    gemm_wo_ep2<<<dim3(16, 64), 256, 0, stream>>>(ACCb, WoT, x, bo, nullf, cover, out);
  } else {
    proj_qkv<<<256, 256, 0, stream>>>(xb, WqT, nullptr, text, WkT, WvT, Kp, Vt, 0);
    gemm_q_f<<<dim3(4, 128), 256, 0, stream>>>(x, WqT, out);
    attn_f<<<1024, 256, 0, stream>>>(out, Kp, Vt, masks);
    gemm_wo_ep<<<256, 512, 0, stream>>>(out, WoT, x, bo, nullf, cover);
  }
}

// Round 14
// 246.652 us; speedup vs baseline: 1.1071x; 1.1071x over previous
//
#include <hip/hip_runtime.h>

// ---------------------------------------------------------------------------
// RegionalCrossAttention on MI355X (gfx950).  fp32 in / fp32 out.
// B=2, n=8, L=4096, Lt=77, d=1024, ctx=768, H=16 heads x 64.
//
// Round-21: FINAL — revert to the round-19 configuration (best measured:
// 250.9 us).  Round-20's 128x64 retile regressed proj_qkv 66->108 us
// (occupancy DROPPED 21.5->14%, MfmaUtil 13.4->8.5%): smaller tiles halve
// MFMA work per barrier interval while keeping per-kt stage+barrier cost,
// and double B re-read traffic.  128x128 at 2-3 blocks/CU is the m97
// structure's operating point for this shape.
//
// Final structure (each component best-of-measured across 13 benches):
//  * transpose_all: 4 weight transposes + cover + x->bf16, one launch.
//  * proj_qkv: Q GEMM on the m97 global_load_lds dbuf structure (128x128,
//    BK=32; 133->62 us vs barrier-free) + K/V projections, one launch.
//  * attn_b: r8 LDS-staged K/V, joint-mi QK^T and PV, P via LDS transpose.
//  * gemm_wo_ep2: m97 structure + fp32 epilogue (cover/bias/null/residual).
// ---------------------------------------------------------------------------

typedef __bf16 bf16;
typedef __bf16 bf16x8 __attribute__((ext_vector_type(8)));
typedef __bf16 bf16x4 __attribute__((ext_vector_type(4)));
typedef float  f32x4  __attribute__((ext_vector_type(4)));

#define MFMA16(a, b, c) __builtin_amdgcn_mfma_f32_16x16x32_bf16((a), (b), (c), 0, 0, 0)

// v_mfma_f32_16x16x32_bf16 layouts (HW-verified, learn_hip m89/m120):
//   A: lane holds A[m = lane&15][k = 8*(lane>>4) + j], j=0..7
//   B: lane holds B[k = 8*(lane>>4) + j][n = lane&15]
//   D: lane,reg r holds D[m = 4*(lane>>4) + r][n = lane&15]

__device__ inline bf16x8 cvt8(const float* p) {
  f32x4 a = *(const f32x4*)p;
  f32x4 b = *(const f32x4*)(p + 4);
  bf16x8 r;
  r[0] = (bf16)a[0]; r[1] = (bf16)a[1]; r[2] = (bf16)a[2]; r[3] = (bf16)a[3];
  r[4] = (bf16)b[0]; r[5] = (bf16)b[1]; r[6] = (bf16)b[2]; r[7] = (bf16)b[3];
  return r;
}

// direct global->LDS DMA, 16B per lane; LDS dest = wave-uniform base + lane*16
__device__ __forceinline__ void gload_lds16(const bf16* g, bf16* l) {
  __builtin_amdgcn_global_load_lds(
      (const __attribute__((address_space(1))) void*)g,
      (__attribute__((address_space(3))) void*)l, 16, 0, 0);
}

// ---------------------------------------------------------------------------
// Weight transposes + cover + x->bf16 conversion, one launch.  grid=(32,145).
// ---------------------------------------------------------------------------
__global__ __launch_bounds__(256) void transpose_all(
    const float* __restrict__ Wq, const float* __restrict__ Wk,
    const float* __restrict__ Wv, const float* __restrict__ Wo,
    bf16* __restrict__ WqT, bf16* __restrict__ WkT,
    bf16* __restrict__ WvT, bf16* __restrict__ WoT,
    const float* __restrict__ mask, float* __restrict__ cover,
    const float* __restrict__ x, bf16* __restrict__ xb) {
  __shared__ bf16 tile[32][33];
  int bx = blockIdx.x;
  int byg = blockIdx.y;
  if (byg == 112) {
    int tid = bx * 256 + threadIdx.x;
    int b = tid >> 12, l = tid & 4095;
    float c = 0.f;
#pragma unroll
    for (int n = 0; n < 8; n++)
      c += (mask[(size_t)(b * 8 + n) * 4096 + l] > 0.5f) ? 1.f : 0.f;
    cover[tid] = c;
    return;
  }
  if (byg >= 113) {
    int gy = byg - 113;  // 0..31
    const size_t blk = (size_t)(gy * 32 + bx) * 1024;
#pragma unroll
    for (int i = 0; i < 4; i++) {
      size_t e = (blk + i * 256 + threadIdx.x) * 8;
      *(bf16x8*)(xb + e) = cvt8(x + e);
    }
    return;
  }
  int tx = threadIdx.x & 31, ty = threadIdx.x >> 5;
  const float* in;
  bf16* out;
  int R, by;
  if (byg < 32)      { in = Wq; out = WqT; R = 1024; by = byg; }
  else if (byg < 56) { in = Wk; out = WkT; R = 768;  by = byg - 32; }
  else if (byg < 80) { in = Wv; out = WvT; R = 768;  by = byg - 56; }
  else               { in = Wo; out = WoT; R = 1024; by = byg - 80; }
  const int C = 1024;
  int c = bx * 32 + tx;
#pragma unroll
  for (int i = 0; i < 32; i += 8) {
    int r = by * 32 + ty + i;
    tile[ty + i][tx] = (bf16)in[(size_t)r * C + c];
  }
  __syncthreads();
#pragma unroll
  for (int i = 0; i < 32; i += 8) {
    out[(size_t)(bx * 32 + ty + i) * R + by * 32 + tx] = tile[tx][ty + i];
  }
}

// ---------------------------------------------------------------------------
// Q GEMM body, m97 structure: Qb = (xb @ WqT^T) * 0.125.
// 128x128 tile, 4 waves (64x64 each), BK=32, dbuf LDS for A and B staged by
// global_load_lds w16.  Stage(next) issued BEFORE ds_read+MFMA of cur; one
// __syncthreads (vmcnt0 drain) per kt.
// ---------------------------------------------------------------------------
__device__ __forceinline__ void gemm_q_body(const bf16* __restrict__ Ab,
                                            const bf16* __restrict__ BT,
                                            bf16* __restrict__ C,
                                            int bxn, int bym) {
  __shared__ __align__(16) bf16 sA[2][128 * 32];
  __shared__ __align__(16) bf16 sB[2][128 * 32];
  const int tid = threadIdx.x;
  const int lane = tid & 63, wave = tid >> 6;
  const int l16 = lane & 15, quad = lane >> 4;
  const int m0 = bym * 128, n0 = bxn * 128;
  const int wm = (wave & 1) * 64, wn = (wave >> 1) * 64;

  const int c0 = tid, c1 = 256 + tid;
  const int ar0 = c0 >> 2, ac0 = (c0 & 3) * 8;
  const int ar1 = c1 >> 2, ac1 = (c1 & 3) * 8;
  const int lo0 = (wave * 64) * 8;          // LDS element offset, issue 0
  const int lo1 = (256 + wave * 64) * 8;    // issue 1

  const bf16* Arow0 = Ab + (size_t)(m0 + ar0) * 1024 + ac0;
  const bf16* Arow1 = Ab + (size_t)(m0 + ar1) * 1024 + ac1;
  const bf16* Brow0 = BT + (size_t)(n0 + ar0) * 1024 + ac0;
  const bf16* Brow1 = BT + (size_t)(n0 + ar1) * 1024 + ac1;

  // prologue: stage kt=0 into buffer 0
  gload_lds16(Arow0, &sA[0][lo0]);
  gload_lds16(Arow1, &sA[0][lo1]);
  gload_lds16(Brow0, &sB[0][lo0]);
  gload_lds16(Brow1, &sB[0][lo1]);

  f32x4 acc[4][4];
#pragma unroll
  for (int i = 0; i < 4; i++)
#pragma unroll
    for (int j = 0; j < 4; j++)
#pragma unroll
      for (int r = 0; r < 4; r++) acc[i][j][r] = 0.f;

  __syncthreads();

  int cur = 0;
  for (int kt = 0; kt < 32; kt++) {
    if (kt + 1 < 32) {
      const int nb = cur ^ 1, ko = (kt + 1) * 32;
      gload_lds16(Arow0 + ko, &sA[nb][lo0]);
      gload_lds16(Arow1 + ko, &sA[nb][lo1]);
      gload_lds16(Brow0 + ko, &sB[nb][lo0]);
      gload_lds16(Brow1 + ko, &sB[nb][lo1]);
    }
    bf16x8 a[4], b[4];
#pragma unroll
    for (int mi = 0; mi < 4; mi++)
      a[mi] = *(const bf16x8*)(&sA[cur][(wm + mi * 16 + l16) * 32 + quad * 8]);
#pragma unroll
    for (int ni = 0; ni < 4; ni++)
      b[ni] = *(const bf16x8*)(&sB[cur][(wn + ni * 16 + l16) * 32 + quad * 8]);
#pragma unroll
    for (int mi = 0; mi < 4; mi++)
#pragma unroll
      for (int ni = 0; ni < 4; ni++) acc[mi][ni] = MFMA16(a[mi], b[ni], acc[mi][ni]);
    __syncthreads();
    cur ^= 1;
  }

#pragma unroll
  for (int mi = 0; mi < 4; mi++)
#pragma unroll
    for (int r = 0; r < 4; r++) {
      int row = m0 + wm + mi * 16 + quad * 4 + r;
#pragma unroll
      for (int ni = 0; ni < 4; ni++)
        C[(size_t)row * 1024 + n0 + wn + ni * 16 + l16] = (bf16)(acc[mi][ni][r] * 0.125f);
    }
}

// ---------------------------------------------------------------------------
// K projection body with padded store: Kp[bn][80][1024] bf16; rows 77..79 = 0.
// ---------------------------------------------------------------------------
__device__ __forceinline__ void gemm_k_body(const float* __restrict__ text,
                                            const bf16* __restrict__ WkT,
                                            bf16* __restrict__ Kp,
                                            int bx, int bn) {
  const int tid = threadIdx.x;
  const int lane = tid & 63, wave = tid >> 6;
  const int l16 = lane & 15, quad = lane >> 4;
  const int m0 = (wave >> 1) * 64;
  const int n0 = bx * 128 + (wave & 1) * 64;
  const float* A = text + (size_t)bn * 77 * 768;
  bf16* dst = Kp + (size_t)bn * 80 * 1024;

  f32x4 acc[4][4];
#pragma unroll
  for (int i = 0; i < 4; i++)
#pragma unroll
    for (int j = 0; j < 4; j++)
#pragma unroll
      for (int r = 0; r < 4; r++) acc[i][j][r] = 0.f;

  for (int k0 = 0; k0 < 768; k0 += 32) {
    bf16x8 a[4], b[4];
#pragma unroll
    for (int mi = 0; mi < 4; mi++) {
      int row = m0 + mi * 16 + l16;
      if (row >= 77) row = 76;
      a[mi] = cvt8(A + (size_t)row * 768 + k0 + quad * 8);
    }
#pragma unroll
    for (int ni = 0; ni < 4; ni++)
      b[ni] = *(const bf16x8*)(WkT + (size_t)(n0 + ni * 16 + l16) * 768 + k0 + quad * 8);
#pragma unroll
    for (int mi = 0; mi < 4; mi++)
#pragma unroll
      for (int ni = 0; ni < 4; ni++) acc[mi][ni] = MFMA16(a[mi], b[ni], acc[mi][ni]);
  }

#pragma unroll
  for (int mi = 0; mi < 4; mi++)
#pragma unroll
    for (int r = 0; r < 4; r++) {
      int t = m0 + mi * 16 + quad * 4 + r;
      if (t < 77) {
#pragma unroll
        for (int ni = 0; ni < 4; ni++)
          dst[(size_t)t * 1024 + n0 + ni * 16 + l16] = (bf16)acc[mi][ni][r];
      } else if (t < 80) {
#pragma unroll
        for (int ni = 0; ni < 4; ni++)
          dst[(size_t)t * 1024 + n0 + ni * 16 + l16] = (bf16)0.f;
      }
    }
}

// ---------------------------------------------------------------------------
// V projection body with TRANSPOSED padded store: Vt[bn][1024][96] bf16.
// ---------------------------------------------------------------------------
__device__ __forceinline__ void gemm_v_body(const float* __restrict__ text,
                                            const bf16* __restrict__ WvT,
                                            bf16* __restrict__ Vt,
                                            int bx, int bn) {
  const int tid = threadIdx.x;
  const int lane = tid & 63, wave = tid >> 6;
  const int l16 = lane & 15, quad = lane >> 4;
  const int m0 = (wave >> 1) * 64;
  const int n0 = bx * 128 + (wave & 1) * 64;
  const float* A = text + (size_t)bn * 77 * 768;
  bf16* dst = Vt + (size_t)bn * 1024 * 96;

  f32x4 acc[4][4];
#pragma unroll
  for (int i = 0; i < 4; i++)
#pragma unroll
    for (int j = 0; j < 4; j++)
#pragma unroll
      for (int r = 0; r < 4; r++) acc[i][j][r] = 0.f;

  for (int k0 = 0; k0 < 768; k0 += 32) {
    bf16x8 a[4], b[4];
#pragma unroll
    for (int mi = 0; mi < 4; mi++) {
      int row = m0 + mi * 16 + l16;
      if (row >= 77) row = 76;
      a[mi] = cvt8(A + (size_t)row * 768 + k0 + quad * 8);
    }
#pragma unroll
    for (int ni = 0; ni < 4; ni++)
      b[ni] = *(const bf16x8*)(WvT + (size_t)(n0 + ni * 16 + l16) * 768 + k0 + quad * 8);
#pragma unroll
    for (int mi = 0; mi < 4; mi++)
#pragma unroll
      for (int ni = 0; ni < 4; ni++) acc[mi][ni] = MFMA16(a[mi], b[ni], acc[mi][ni]);
  }

#pragma unroll
  for (int mi = 0; mi < 4; mi++) {
    int t0 = m0 + mi * 16 + quad * 4;
#pragma unroll
    for (int ni = 0; ni < 4; ni++) {
      int col = n0 + ni * 16 + l16;
      bf16* cbase = dst + (size_t)col * 96;
      if (t0 + 3 < 77) {
        bf16x4 w;
        w[0] = (bf16)acc[mi][ni][0]; w[1] = (bf16)acc[mi][ni][1];
        w[2] = (bf16)acc[mi][ni][2]; w[3] = (bf16)acc[mi][ni][3];
        *(bf16x4*)(cbase + t0) = w;
      } else {
#pragma unroll
        for (int r = 0; r < 4; r++) {
          int t = t0 + r;
          if (t < 77)      cbase[t] = (bf16)acc[mi][ni][r];
          else if (t < 96) cbase[t] = (bf16)0.f;
        }
      }
    }
  }
}

// ---------------------------------------------------------------------------
// Fused Q + K + V projections.  Flat grid of qcount+256 blocks.
// ---------------------------------------------------------------------------
__global__ __launch_bounds__(256) void proj_qkv(const bf16* __restrict__ xb,
                                                const bf16* __restrict__ WqT,
                                                bf16* __restrict__ Qb,
                                                const float* __restrict__ text,
                                                const bf16* __restrict__ WkT,
                                                const bf16* __restrict__ WvT,
                                                bf16* __restrict__ Kp,
                                                bf16* __restrict__ Vt,
                                                int qcount) {
  const int bid = blockIdx.x;
  if (bid < qcount) {
    gemm_q_body(xb, WqT, Qb, bid >> 6, bid & 63);
  } else {
    const int r = bid - qcount;
    const int bx = r & 7, bn = (r >> 3) & 15, kz = r >> 7;
    if (kz == 0) gemm_k_body(text, WkT, Kp, bx, bn);
    else         gemm_v_body(text, WvT, Vt, bx, bn);
  }
}

// Q GEMM (fallback): fp32 in, fp32 out, pre-scaled by 0.125
__global__ __launch_bounds__(256) void gemm_q_f(const float* __restrict__ A,
                                                const bf16* __restrict__ BT,
                                                float* __restrict__ C) {
  const int tid = threadIdx.x;
  const int lane = tid & 63, wave = tid >> 6;
  const int l16 = lane & 15, quad = lane >> 4;
  const int m0 = blockIdx.y * 64;
  const int n0 = blockIdx.x * 256 + wave * 64;

  f32x4 acc[4][4];
#pragma unroll
  for (int i = 0; i < 4; i++)
#pragma unroll
    for (int j = 0; j < 4; j++)
#pragma unroll
      for (int r = 0; r < 4; r++) acc[i][j][r] = 0.f;

  for (int kt = 0; kt < 32; kt++) {
    bf16x8 a[4], b[4];
#pragma unroll
    for (int mi = 0; mi < 4; mi++)
      a[mi] = cvt8(A + (size_t)(m0 + mi * 16 + l16) * 1024 + kt * 32 + quad * 8);
#pragma unroll
    for (int ni = 0; ni < 4; ni++)
      b[ni] = *(const bf16x8*)(BT + (size_t)(n0 + ni * 16 + l16) * 1024 + kt * 32 + quad * 8);
#pragma unroll
    for (int mi = 0; mi < 4; mi++)
#pragma unroll
      for (int ni = 0; ni < 4; ni++) acc[mi][ni] = MFMA16(a[mi], b[ni], acc[mi][ni]);
  }

#pragma unroll
  for (int mi = 0; mi < 4; mi++)
#pragma unroll
    for (int r = 0; r < 4; r++) {
      int row = m0 + mi * 16 + quad * 4 + r;
#pragma unroll
      for (int ni = 0; ni < 4; ni++)
        C[(size_t)row * 1024 + n0 + ni * 16 + l16] = acc[mi][ni][r] * 0.125f;
    }
}

// ---------------------------------------------------------------------------
// Attention core (round-8 staging structure + joint-mi PV).
// LDS: kl 11520 + vl 13312 + p_lds 13312 = 38144 B -> 4 blocks/CU.
// ---------------------------------------------------------------------------
template <typename OutT, typename InT>
__device__ __forceinline__ void attn_body(const InT* Qsrc, OutT* Odst,
                                          const bf16* __restrict__ Kp,
                                          const bf16* __restrict__ Vt,
                                          const float* __restrict__ mask) {
  __shared__ __align__(16) bf16 kl[80 * 72];
  __shared__ __align__(16) bf16 vl[64 * 104];
  __shared__ __align__(16) bf16 p_lds[4][16 * 104];
  const int tid = threadIdx.x;
  const int lane = tid & 63, wave = tid >> 6;
  const int l16 = lane & 15, quad = lane >> 4;
  const int bid = blockIdx.x;
  const int qg = bid & 31;
  const int h = (bid >> 5) & 15;
  const int b = bid >> 9;
  const int qrow0 = qg * 128 + wave * 32;
  bf16* pl = &p_lds[wave][0];

  for (int i = lane; i < 16 * 16; i += 64) {
    int r = i >> 4, c = 80 + (i & 15);
    pl[r * 104 + c] = (bf16)0.f;
  }

  bf16x8 qf[2][2];
#pragma unroll
  for (int mi = 0; mi < 2; mi++)
#pragma unroll
    for (int ks = 0; ks < 2; ks++) {
      const InT* qp = Qsrc + (size_t)(b * 4096 + qrow0 + mi * 16 + l16) * 1024 +
                      h * 64 + ks * 32 + quad * 8;
      if constexpr (sizeof(InT) == 4) qf[mi][ks] = cvt8((const float*)qp);
      else                            qf[mi][ks] = *(const bf16x8*)qp;
    }

  unsigned rbits[2];
#pragma unroll
  for (int mi = 0; mi < 2; mi++) {
    unsigned m = 0;
#pragma unroll
    for (int n = 0; n < 8; n++)
      if (mask[(size_t)(b * 8 + n) * 4096 + qrow0 + mi * 16 + l16] > 0.5f)
        m |= (1u << n);
    rbits[mi] = m;
  }

  f32x4 oacc[2][4];
#pragma unroll
  for (int mi = 0; mi < 2; mi++)
#pragma unroll
    for (int nt = 0; nt < 4; nt++)
#pragma unroll
      for (int r = 0; r < 4; r++) oacc[mi][nt][r] = 0.f;

  for (int n = 0; n < 8; n++) {
    const int bn = b * 8 + n;
    const bf16* Ksrc = Kp + (size_t)bn * 80 * 1024 + h * 64;
    const bf16* Vsrc = Vt + (size_t)bn * 1024 * 96 + (size_t)h * 64 * 96;

    for (int i = tid; i < 640; i += 256) {
      int row = i >> 3, c8 = (i & 7) * 8;
      *(bf16x8*)(kl + row * 72 + c8) = *(const bf16x8*)(Ksrc + (size_t)row * 1024 + c8);
    }
    for (int i = tid; i < 768; i += 256) {
      int row = i / 12, c8 = (i % 12) * 8;
      *(bf16x8*)(vl + row * 104 + c8) = *(const bf16x8*)(Vsrc + (size_t)row * 96 + c8);
    }
    __syncthreads();

    f32x4 s[2][5];
#pragma unroll
    for (int mi = 0; mi < 2; mi++)
#pragma unroll
      for (int tt = 0; tt < 5; tt++)
#pragma unroll
        for (int r = 0; r < 4; r++) s[mi][tt][r] = 0.f;

#pragma unroll
    for (int tt = 0; tt < 5; tt++) {
      int t = tt * 16 + l16;
      bf16x8 kf0 = *(const bf16x8*)(kl + t * 72 + quad * 8);
      bf16x8 kf1 = *(const bf16x8*)(kl + t * 72 + 32 + quad * 8);
#pragma unroll
      for (int mi = 0; mi < 2; mi++) {
        s[mi][tt] = MFMA16(kf0, qf[mi][0], s[mi][tt]);
        s[mi][tt] = MFMA16(kf1, qf[mi][1], s[mi][tt]);
      }
    }

    bf16x8 pfr[2][3];
#pragma unroll
    for (int mi = 0; mi < 2; mi++) {
      float sum = 0.f;
#pragma unroll
      for (int tt = 0; tt < 5; tt++) {
#pragma unroll
        for (int r = 0; r < 4; r++) {
          float e = __expf(s[mi][tt][r]);  // 0.125 scale folded into Q GEMM
          if (tt == 4 && quad * 4 + r >= 13) e = 0.f;
          s[mi][tt][r] = e;
          sum += e;
        }
      }
      sum += __shfl_xor(sum, 16);
      sum += __shfl_xor(sum, 32);
      float rg = ((rbits[mi] >> n) & 1u) ? 1.f : 0.f;
      float scale = rg / sum;
#pragma unroll
      for (int tt = 0; tt < 5; tt++) {
        bf16x4 w;
#pragma unroll
        for (int r = 0; r < 4; r++) w[r] = (bf16)(s[mi][tt][r] * scale);
        *(bf16x4*)(pl + l16 * 104 + tt * 16 + quad * 4) = w;
      }
#pragma unroll
      for (int ks = 0; ks < 3; ks++)
        pfr[mi][ks] = *(const bf16x8*)(pl + l16 * 104 + ks * 32 + quad * 8);
    }

#pragma unroll
    for (int ks = 0; ks < 3; ks++) {
#pragma unroll
      for (int nt = 0; nt < 4; nt++) {
        bf16x8 vf = *(const bf16x8*)(vl + (nt * 16 + l16) * 104 + ks * 32 + quad * 8);
        oacc[0][nt] = MFMA16(pfr[0][ks], vf, oacc[0][nt]);
        oacc[1][nt] = MFMA16(pfr[1][ks], vf, oacc[1][nt]);
      }
    }
    __syncthreads();
  }

#pragma unroll
  for (int mi = 0; mi < 2; mi++)
#pragma unroll
    for (int r = 0; r < 4; r++) {
      size_t row = (size_t)(b * 4096 + qrow0 + mi * 16 + quad * 4 + r);
#pragma unroll
      for (int nt = 0; nt < 4; nt++)
        Odst[row * 1024 + h * 64 + nt * 16 + l16] = (OutT)oacc[mi][nt][r];
    }
}

// fast: Q bf16 (in d_out), ACC bf16 (in ws)
__global__ __launch_bounds__(256, 4) void attn_b(const bf16* Qb, bf16* ACCb,
                                                 const bf16* __restrict__ Kp,
                                                 const bf16* __restrict__ Vt,
                                                 const float* __restrict__ mask) {
  attn_body<bf16, bf16>(Qb, ACCb, Kp, Vt, mask);
}
// fallback: fp32 in-place on d_out
__global__ __launch_bounds__(256, 4) void attn_f(float* QO,
                                                 const bf16* __restrict__ Kp,
                                                 const bf16* __restrict__ Vt,
                                                 const float* __restrict__ mask) {
  attn_body<float, float>(QO, QO, Kp, Vt, mask);
}

// ---------------------------------------------------------------------------
// Fast-path final GEMM, m97 structure: out = ACCb @ WoT^T + epilogue.
// Same staged body as gemm_q_body (identical shape); fp32 epilogue.
// ---------------------------------------------------------------------------
__global__ __launch_bounds__(256) void gemm_wo_ep2(const bf16* __restrict__ A,
                                                   const bf16* __restrict__ BT,
                                                   const float* __restrict__ x,
                                                   const float* __restrict__ bo,
                                                   const float* __restrict__ nullf,
                                                   const float* __restrict__ cover,
                                                   float* __restrict__ out) {
  __shared__ __align__(16) bf16 sA[2][128 * 32];
  __shared__ __align__(16) bf16 sB[2][128 * 32];
  const int tid = threadIdx.x;
  const int lane = tid & 63, wave = tid >> 6;
  const int l16 = lane & 15, quad = lane >> 4;
  const int m0 = blockIdx.y * 128, n0 = blockIdx.x * 128;
  const int wm = (wave & 1) * 64, wn = (wave >> 1) * 64;

  const int c0 = tid, c1 = 256 + tid;
  const int ar0 = c0 >> 2, ac0 = (c0 & 3) * 8;
  const int ar1 = c1 >> 2, ac1 = (c1 & 3) * 8;
  const int lo0 = (wave * 64) * 8;
  const int lo1 = (256 + wave * 64) * 8;

  const bf16* Arow0 = A + (size_t)(m0 + ar0) * 1024 + ac0;
  const bf16* Arow1 = A + (size_t)(m0 + ar1) * 1024 + ac1;
  const bf16* Brow0 = BT + (size_t)(n0 + ar0) * 1024 + ac0;
  const bf16* Brow1 = BT + (size_t)(n0 + ar1) * 1024 + ac1;

  gload_lds16(Arow0, &sA[0][lo0]);
  gload_lds16(Arow1, &sA[0][lo1]);
  gload_lds16(Brow0, &sB[0][lo0]);
  gload_lds16(Brow1, &sB[0][lo1]);

  f32x4 acc[4][4];
#pragma unroll
  for (int i = 0; i < 4; i++)
#pragma unroll
    for (int j = 0; j < 4; j++)
#pragma unroll
      for (int r = 0; r < 4; r++) acc[i][j][r] = 0.f;

  __syncthreads();

  int cur = 0;
  for (int kt = 0; kt < 32; kt++) {
    if (kt + 1 < 32) {
      const int nb = cur ^ 1, ko = (kt + 1) * 32;
      gload_lds16(Arow0 + ko, &sA[nb][lo0]);
      gload_lds16(Arow1 + ko, &sA[nb][lo1]);
      gload_lds16(Brow0 + ko, &sB[nb][lo0]);
      gload_lds16(Brow1 + ko, &sB[nb][lo1]);
    }
    bf16x8 a[4], b[4];
#pragma unroll
    for (int mi = 0; mi < 4; mi++)
      a[mi] = *(const bf16x8*)(&sA[cur][(wm + mi * 16 + l16) * 32 + quad * 8]);
#pragma unroll
    for (int ni = 0; ni < 4; ni++)
      b[ni] = *(const bf16x8*)(&sB[cur][(wn + ni * 16 + l16) * 32 + quad * 8]);
#pragma unroll
    for (int mi = 0; mi < 4; mi++)
#pragma unroll
      for (int ni = 0; ni < 4; ni++) acc[mi][ni] = MFMA16(a[mi], b[ni], acc[mi][ni]);
    __syncthreads();
    cur ^= 1;
  }

#pragma unroll
  for (int mi = 0; mi < 4; mi++)
#pragma unroll
    for (int r = 0; r < 4; r++) {
      int row = m0 + wm + mi * 16 + quad * 4 + r;
      float cv = cover[row];
#pragma unroll
      for (int ni = 0; ni < 4; ni++) {
        int col = n0 + wn + ni * 16 + l16;
        float v = acc[mi][ni][r] + cv * bo[col] + (1.f - cv) * nullf[col] +
                  x[(size_t)row * 1024 + col];
        out[(size_t)row * 1024 + col] = v;
      }
    }
}

// ---------------------------------------------------------------------------
// Fallback in-place final GEMM (round-7 version).
// ---------------------------------------------------------------------------
__global__ __launch_bounds__(512) void gemm_wo_ep(float* QO,
                                                  const bf16* __restrict__ WoT,
                                                  const float* __restrict__ x,
                                                  const float* __restrict__ bo,
                                                  const float* __restrict__ nullf,
                                                  const float* __restrict__ cover) {
  __shared__ __align__(16) bf16 lds_a[32 * 32 * 32];
  const int tid = threadIdx.x;
  const int lane = tid & 63, wv = tid >> 6;
  const int l16 = lane & 15, quad = lane >> 4;
  const int m0 = blockIdx.x * 32;

#pragma unroll
  for (int c = 0; c < 16; c++) {
    int ch = c * 512 + tid;
    int row = ch >> 8;
    int pos4 = (ch & 255) * 4;
    int kt = pos4 >> 5, kin = pos4 & 31;
    f32x4 v = *(const f32x4*)(QO + (size_t)(m0 + row) * 1024 + pos4);
    bf16x4 w;
    w[0] = (bf16)v[0]; w[1] = (bf16)v[1]; w[2] = (bf16)v[2]; w[3] = (bf16)v[3];
    *(bf16x4*)(lds_a + kt * 1024 + row * 32 + kin) = w;
  }
  __syncthreads();

  const int n0 = wv * 128;
  f32x4 acc[2][8];
#pragma unroll
  for (int mi = 0; mi < 2; mi++)
#pragma unroll
    for (int ni = 0; ni < 8; ni++)
#pragma unroll
      for (int r = 0; r < 4; r++) acc[mi][ni][r] = 0.f;

  for (int kt = 0; kt < 32; kt++) {
    bf16x8 a[2];
#pragma unroll
    for (int mi = 0; mi < 2; mi++)
      a[mi] = *(const bf16x8*)(lds_a + kt * 1024 + (mi * 16 + l16) * 32 + quad * 8);
    bf16x8 bfr[8];
#pragma unroll
    for (int ni = 0; ni < 8; ni++)
      bfr[ni] = *(const bf16x8*)(WoT + (size_t)(n0 + ni * 16 + l16) * 1024 + kt * 32 + quad * 8);
#pragma unroll
    for (int mi = 0; mi < 2; mi++)
#pragma unroll
      for (int ni = 0; ni < 8; ni++) acc[mi][ni] = MFMA16(a[mi], bfr[ni], acc[mi][ni]);
  }

#pragma unroll
  for (int mi = 0; mi < 2; mi++)
#pragma unroll
    for (int r = 0; r < 4; r++) {
      int row = m0 + mi * 16 + quad * 4 + r;
      float cv = cover[row];
#pragma unroll
      for (int ni = 0; ni < 8; ni++) {
        int col = n0 + ni * 16 + l16;
        float v = acc[mi][ni][r] + cv * bo[col] + (1.f - cv) * nullf[col] +
                  x[(size_t)row * 1024 + col];
        QO[(size_t)row * 1024 + col] = v;
      }
    }
}

// ---------------------------------------------------------------------------
extern "C" void kernel_launch(void* const* d_in, const int* in_sizes, int n_in,
                              void* d_out, int out_size, void* d_ws, size_t ws_size,
                              hipStream_t stream) {
  const float* x     = (const float*)d_in[0];
  const float* masks = (const float*)d_in[1];
  const float* text  = (const float*)d_in[2];
  const float* Wq    = (const float*)d_in[3];
  const float* Wk    = (const float*)d_in[4];
  const float* Wv    = (const float*)d_in[5];
  const float* Wo    = (const float*)d_in[6];
  const float* bo    = (const float*)d_in[7];
  const float* nullf = (const float*)d_in[8];
  float* out = (float*)d_out;

  bf16* ws  = (bf16*)d_ws;
  bf16* WqT = ws;                  // 1024*1024
  bf16* WkT = WqT + 1048576;       // 1024*768
  bf16* WvT = WkT + 786432;        // 1024*768
  bf16* WoT = WvT + 786432;        // 1024*1024
  bf16* Kp  = WoT + 1048576;       // 16*80*1024
  bf16* Vt  = Kp + 1310720;        // 16*1024*96
  float* cover = (float*)(Vt + 1572864);          // 8192 f32
  bf16* ACCb = (bf16*)(cover + 8192);             // 8192*1024 bf16 (fast path)
  const size_t NEEDED = 13139968 + 16777216;      // 29,917,184 B

  // d_out (32 MB) doubles as scratch before the final GEMM:
  //   first half  : Qb  bf16[8192*1024]
  //   second half : xb  bf16[8192*1024]  (x pre-converted)
  bf16* Qb = (bf16*)d_out;
  bf16* xb = (bf16*)d_out + 8388608;

  transpose_all<<<dim3(32, 145), 256, 0, stream>>>(Wq, Wk, Wv, Wo, WqT, WkT, WvT, WoT,
                                                   masks, cover, x, xb);

  if (ws_size >= NEEDED) {
    proj_qkv<<<768, 256, 0, stream>>>(xb, WqT, Qb, text, WkT, WvT, Kp, Vt, 512);
    attn_b<<<1024, 256, 0, stream>>>(Qb, ACCb, Kp, Vt, masks);
    gemm_wo_ep2<<<dim3(8, 64), 256, 0, stream>>>(ACCb, WoT, x, bo, nullf, cover, out);
  } else {
    proj_qkv<<<256, 256, 0, stream>>>(xb, WqT, nullptr, text, WkT, WvT, Kp, Vt, 0);
    gemm_q_f<<<dim3(4, 128), 256, 0, stream>>>(x, WqT, out);
    attn_f<<<1024, 256, 0, stream>>>(out, Kp, Vt, masks);
    gemm_wo_ep<<<256, 512, 0, stream>>>(out, WoT, x, bo, nullf, cover);
  }
}